// Round 1
// baseline (1419.861 us; speedup 1.0000x reference)
//
#include <hip/hip_runtime.h>
#include <math.h>

#define B_SEG 128
#define HDIM 512
#define MIDD 2048
#define NANS 3129
#define NNODES 131072
#define NEDGES 262144
#define CHUNKS 8

__device__ __forceinline__ int lower_bound_i(const int* __restrict__ a, int n, int v) {
    int lo = 0, hi = n;
    while (lo < hi) { int mid = (lo + hi) >> 1; if (a[mid] < v) lo = mid + 1; else hi = mid; }
    return lo;
}

// One block per (segment b, row-chunk); grid.y selects which pool.
// 256 threads: 128 col-groups (float4) x 2 row-parallel. Fully coalesced 4KB/iter.
__global__ __launch_bounds__(256) void pool_kernel(
    const float* __restrict__ f0, const int* __restrict__ s0, int n0,
    const float* __restrict__ f1, const int* __restrict__ s1, int n1,
    const float* __restrict__ f2, const int* __restrict__ s2, int n2,
    float* __restrict__ sums, int* __restrict__ counts)
{
    int pool = blockIdx.y;
    const float* feat = (pool == 0) ? f0 : ((pool == 1) ? f1 : f2);
    const int*  seg   = (pool == 0) ? s0 : ((pool == 1) ? s1 : s2);
    int n             = (pool == 0) ? n0 : ((pool == 1) ? n1 : n2);

    int b     = blockIdx.x / CHUNKS;
    int chunk = blockIdx.x % CHUNKS;

    int start = lower_bound_i(seg, n, b);
    int end   = lower_bound_i(seg, n, b + 1);
    int cnt   = end - start;
    if (chunk == 0 && threadIdx.x == 0) counts[pool * B_SEG + b] = cnt;

    int cs = start + (int)(((long long)cnt * chunk) / CHUNKS);
    int ce = start + (int)(((long long)cnt * (chunk + 1)) / CHUNKS);

    int c4 = threadIdx.x & 127;   // column group (4 floats)
    int rp = threadIdx.x >> 7;    // 0/1 row parallel

    float4 acc = make_float4(0.f, 0.f, 0.f, 0.f);
    for (int r = cs + rp; r < ce; r += 2) {
        const float4 v = *(const float4*)(feat + (size_t)r * HDIM + c4 * 4);
        acc.x += v.x; acc.y += v.y; acc.z += v.z; acc.w += v.w;
    }
    float* dst = sums + (size_t)pool * B_SEG * HDIM + (size_t)b * HDIM + c4 * 4;
    atomicAdd(dst + 0, acc.x);
    atomicAdd(dst + 1, acc.y);
    atomicAdd(dst + 2, acc.z);
    atomicAdd(dst + 3, acc.w);
}

// h_pre[b, c<512]  = 2*bqe[c]  + 2*img_edge_mean[b,c]            (kg_edges == img_edges, source bug)
// h_pre[b, c>=512] = 2*bqn[c'] + img_node_mean[b,c'] + kg_node_mean[b,c']
__global__ __launch_bounds__(256) void init_hpre(
    const float* __restrict__ sums, const int* __restrict__ counts,
    const float* __restrict__ bqe, const float* __restrict__ bqn,
    float* __restrict__ hpre)
{
    int j = blockIdx.x * 256 + threadIdx.x;
    if (j >= B_SEG * 1024) return;
    int b = j >> 10, c = j & 1023;
    const float* sums_in = sums;                        // pool0: img_node
    const float* sums_kn = sums + B_SEG * HDIM;         // pool1: kg_node
    const float* sums_ie = sums + 2 * B_SEG * HDIM;     // pool2: img_edge
    float v;
    if (c < HDIM) {
        float ce = fmaxf((float)counts[2 * B_SEG + b], 1.f);
        v = 2.f * bqe[c] + 2.f * sums_ie[b * HDIM + c] / ce;
    } else {
        int c2 = c - HDIM;
        float ci = fmaxf((float)counts[0 * B_SEG + b], 1.f);
        float ck = fmaxf((float)counts[1 * B_SEG + b], 1.f);
        v = 2.f * bqn[c2] + sums_in[b * HDIM + c2] / ci + sums_kn[b * HDIM + c2] / ck;
    }
    hpre[j] = v;
}

__global__ __launch_bounds__(256) void bcast_bias(
    const float* __restrict__ bias, float* __restrict__ C, int rows, int cols)
{
    int j = blockIdx.x * 256 + threadIdx.x;
    if (j >= rows * cols) return;
    C[j] = bias[j % cols];
}

__global__ __launch_bounds__(256) void elu_k(
    const float* __restrict__ x, float* __restrict__ y, int n)
{
    int j = blockIdx.x * 256 + threadIdx.x;
    if (j >= n) return;
    float v = x[j];
    y[j] = (v > 0.f) ? v : (expf(v) - 1.f);
}

// Split-K f32 GEMM: C[m, coff+n] += alpha * sum_k A[m,k]*B[k,n] over this block's K range.
// 64x64 tile, BK=16, 256 threads, 4x4 micro-tile, atomicAdd epilogue.
__global__ __launch_bounds__(256) void gemm_splitk(
    const float* __restrict__ A, const float* __restrict__ Bm, float* __restrict__ C,
    int M, int N, int K, int ldc, int coff, float alpha, int kPerSplit)
{
    __shared__ float As[16][65];
    __shared__ float Bs[16][64];
    int tid = threadIdx.x;
    int tx = tid & 15, ty = tid >> 4;
    int n0 = blockIdx.x * 64;
    int m0 = blockIdx.y * 64;
    int k0 = blockIdx.z * kPerSplit;

    int la_k = tid & 15;   // 0..15
    int la_m = tid >> 4;   // 0..15
    int lb_n = tid & 63;   // 0..63
    int lb_k = tid >> 6;   // 0..3

    float acc[4][4];
#pragma unroll
    for (int i = 0; i < 4; i++)
#pragma unroll
        for (int j = 0; j < 4; j++) acc[i][j] = 0.f;

    for (int kk = k0; kk < k0 + kPerSplit; kk += 16) {
#pragma unroll
        for (int i = 0; i < 4; i++) {
            int m = la_m + i * 16;
            As[la_k][m] = A[(size_t)(m0 + m) * K + kk + la_k];
        }
#pragma unroll
        for (int i = 0; i < 4; i++) {
            int k = lb_k + i * 4;
            int n = n0 + lb_n;
            Bs[k][lb_n] = (n < N) ? Bm[(size_t)(kk + k) * N + n] : 0.f;
        }
        __syncthreads();
#pragma unroll
        for (int k = 0; k < 16; k++) {
            float a0 = As[k][ty * 4 + 0], a1 = As[k][ty * 4 + 1];
            float a2 = As[k][ty * 4 + 2], a3 = As[k][ty * 4 + 3];
            float b0 = Bs[k][tx * 4 + 0], b1 = Bs[k][tx * 4 + 1];
            float b2 = Bs[k][tx * 4 + 2], b3 = Bs[k][tx * 4 + 3];
            acc[0][0] += a0 * b0; acc[0][1] += a0 * b1; acc[0][2] += a0 * b2; acc[0][3] += a0 * b3;
            acc[1][0] += a1 * b0; acc[1][1] += a1 * b1; acc[1][2] += a1 * b2; acc[1][3] += a1 * b3;
            acc[2][0] += a2 * b0; acc[2][1] += a2 * b1; acc[2][2] += a2 * b2; acc[2][3] += a2 * b3;
            acc[3][0] += a3 * b0; acc[3][1] += a3 * b1; acc[3][2] += a3 * b2; acc[3][3] += a3 * b3;
        }
        __syncthreads();
    }

#pragma unroll
    for (int i = 0; i < 4; i++) {
        int row = m0 + ty * 4 + i;  // M is a multiple of 64
#pragma unroll
        for (int j = 0; j < 4; j++) {
            int col = n0 + tx * 4 + j;
            if (col < N) atomicAdd(&C[(size_t)row * ldc + coff + col], alpha * acc[i][j]);
        }
    }
}

extern "C" void kernel_launch(void* const* d_in, const int* in_sizes, int n_in,
                              void* d_out, int out_size, void* d_ws, size_t ws_size,
                              hipStream_t stream) {
    const float* question      = (const float*)d_in[0];
    const float* img_node_feat = (const float*)d_in[1];
    const float* kg_node_feat  = (const float*)d_in[2];
    const float* img_edge_feat = (const float*)d_in[3];
    // d_in[4] kg_edge_feat: unused (source bug: kg_edges pooled from img edges)
    const int* img_node_seg = (const int*)d_in[5];
    const int* kg_node_seg  = (const int*)d_in[6];
    const int* img_edge_seg = (const int*)d_in[7];
    // d_in[8] kg_edge_seg: unused
    const float* Wqe = (const float*)d_in[9];
    const float* bqe = (const float*)d_in[10];
    const float* Wqn = (const float*)d_in[11];
    const float* bqn = (const float*)d_in[12];
    const float* W1  = (const float*)d_in[13];
    const float* b1  = (const float*)d_in[14];
    const float* W2  = (const float*)d_in[15];
    const float* b2  = (const float*)d_in[16];
    float* out = (float*)d_out;

    char* ws = (char*)d_ws;
    const size_t sums_bytes  = (size_t)3 * B_SEG * HDIM * 4;   // 786432
    const size_t cnt_bytes   = (size_t)3 * B_SEG * 4;          // 1536
    float* sums  = (float*)ws;
    int*   counts = (int*)(ws + sums_bytes);
    float* hpre  = (float*)(ws + sums_bytes + cnt_bytes);                          // 128*1024
    float* h_acc = (float*)(ws + sums_bytes + cnt_bytes + (size_t)B_SEG * 1024 * 4); // 128*2048
    float* h     = (float*)(ws + sums_bytes + cnt_bytes + (size_t)B_SEG * 1024 * 4 + (size_t)B_SEG * MIDD * 4);

    // zero pool accumulators + counts
    hipMemsetAsync(d_ws, 0, sums_bytes + cnt_bytes, stream);

    // 1) segment sums (3 pools in one launch)
    dim3 pgrid(B_SEG * CHUNKS, 3);
    pool_kernel<<<pgrid, 256, 0, stream>>>(
        img_node_feat, img_node_seg, NNODES,
        kg_node_feat,  kg_node_seg,  NNODES,
        img_edge_feat, img_edge_seg, NEDGES,
        sums, counts);

    // 2) h_pre init from pooled means + biases
    init_hpre<<<(B_SEG * 1024 + 255) / 256, 256, 0, stream>>>(sums, counts, bqe, bqn, hpre);

    // 3) h_pre[:, :512] += 2 * question @ Wqe ; h_pre[:, 512:] += 2 * question @ Wqn
    gemm_splitk<<<dim3(8, 2, 8), 256, 0, stream>>>(question, Wqe, hpre, 128, 512, 1024, 1024, 0,   2.f, 128);
    gemm_splitk<<<dim3(8, 2, 8), 256, 0, stream>>>(question, Wqn, hpre, 128, 512, 1024, 1024, 512, 2.f, 128);

    // 4) h_acc = b1 ; h_acc += h_pre @ W1 ; h = elu(h_acc)
    bcast_bias<<<(B_SEG * MIDD + 255) / 256, 256, 0, stream>>>(b1, h_acc, B_SEG, MIDD);
    gemm_splitk<<<dim3(32, 2, 8), 256, 0, stream>>>(hpre, W1, h_acc, 128, MIDD, 1024, MIDD, 0, 1.f, 128);
    elu_k<<<(B_SEG * MIDD + 255) / 256, 256, 0, stream>>>(h_acc, h, B_SEG * MIDD);

    // 5) out = b2 ; out += h @ W2
    bcast_bias<<<(B_SEG * NANS + 255) / 256, 256, 0, stream>>>(b2, out, B_SEG, NANS);
    gemm_splitk<<<dim3((NANS + 63) / 64, 2, 8), 256, 0, stream>>>(h, W2, out, 128, NANS, 2048, NANS, 0, 1.f, 256);
}